// Round 14
// baseline (1540.785 us; speedup 1.0000x reference)
//
#include <hip/hip_runtime.h>
#include <stdint.h>
#include <stddef.h>

// ---------------------------------------------------------------------------
// TwoHemiRNNTanh_asymmetric_single_readout  (B=512, T=400, hidden 258)
// R14 = R13 with the DPP ctrl made a template parameter (builtin requires a
// constant integer). W stationary in LDS (132-dword row stride, conflict-free
// b128 reads); producer/consumer wave split (512 consumers: pure LDS+VALU
// step loop; 256 producers: RNG C-gen one step ahead, hs/zs flush one step
// behind). R8-R12 counters proved the scan was W-bandwidth-bound through
// L1/L2 (262 KB/CU/step ~= 4100cy = measured step time); LDS path is ~4x
// cheaper and consumer register pressure drops to ~45.
// ---------------------------------------------------------------------------

typedef uint32_t u32x4 __attribute__((ext_vector_type(4)));
typedef __fp16   f16x2 __attribute__((ext_vector_type(2)));

#define TF_ROUND(x0, x1, r) { x0 += x1; x1 = ((x1) << (r)) | ((x1) >> (32 - (r))); x1 ^= x0; }

__host__ __device__ inline void tf2x32(uint32_t k0, uint32_t k1, uint32_t x0, uint32_t x1,
                                       uint32_t& o0, uint32_t& o1) {
  uint32_t ks2 = k0 ^ k1 ^ 0x1BD11BDAu;
  x0 += k0; x1 += k1;
  TF_ROUND(x0, x1, 13) TF_ROUND(x0, x1, 15) TF_ROUND(x0, x1, 26) TF_ROUND(x0, x1, 6)
  x0 += k1; x1 += ks2 + 1u;
  TF_ROUND(x0, x1, 17) TF_ROUND(x0, x1, 29) TF_ROUND(x0, x1, 16) TF_ROUND(x0, x1, 24)
  x0 += ks2; x1 += k0 + 2u;
  TF_ROUND(x0, x1, 13) TF_ROUND(x0, x1, 15) TF_ROUND(x0, x1, 26) TF_ROUND(x0, x1, 6)
  x0 += k0; x1 += k1 + 3u;
  TF_ROUND(x0, x1, 17) TF_ROUND(x0, x1, 29) TF_ROUND(x0, x1, 16) TF_ROUND(x0, x1, 24)
  x0 += k1; x1 += ks2 + 4u;
  TF_ROUND(x0, x1, 13) TF_ROUND(x0, x1, 15) TF_ROUND(x0, x1, 26) TF_ROUND(x0, x1, 6)
  x0 += ks2; x1 += k0 + 5u;
  o0 = x0; o1 = x1;
}

__device__ __forceinline__ float jax_erfinv(float x) {
  float w = -log1pf(-x * x);
  float p;
  if (w < 5.0f) {
    w -= 2.5f;
    p = 2.81022636e-08f;
    p = fmaf(p, w, 3.43273939e-07f);
    p = fmaf(p, w, -3.5233877e-06f);
    p = fmaf(p, w, -4.39150654e-06f);
    p = fmaf(p, w, 0.00021858087f);
    p = fmaf(p, w, -0.00125372503f);
    p = fmaf(p, w, -0.00417768164f);
    p = fmaf(p, w, 0.246640727f);
    p = fmaf(p, w, 1.50140941f);
  } else {
    w = sqrtf(w) - 3.0f;
    p = -0.000200214257f;
    p = fmaf(p, w, 0.000100950558f);
    p = fmaf(p, w, 0.00134934322f);
    p = fmaf(p, w, -0.00367342844f);
    p = fmaf(p, w, 0.00573950773f);
    p = fmaf(p, w, -0.0076224613f);
    p = fmaf(p, w, 0.00943887047f);
    p = fmaf(p, w, 1.00167406f);
    p = fmaf(p, w, 2.83297682f);
  }
  return p * x;
}

__device__ __forceinline__ float uni_from_bits(uint32_t bits) {
  float f = __uint_as_float((bits >> 9) | 0x3f800000u) - 1.0f;
  float x = f * 2.0f + (-0.99999994f);
  return fmaxf(-0.99999994f, x);
}

__device__ __forceinline__ float noise_from_bits(uint32_t bits) {
  float n = 1.41421356f * jax_erfinv(uni_from_bits(bits));
  return 0.15811388f * n;   // sqrt(2/A)*SIG = sqrt(10)*0.05
}

__device__ __forceinline__ float my_tanh(float x) {
  float e = __expf(2.0f * x);
  return 1.0f - 2.0f / (e + 1.0f);
}

__device__ __forceinline__ uint32_t packh2(float a, float b) {
  f16x2 h = __builtin_amdgcn_cvt_pkrtz(a, b);
  return __builtin_bit_cast(uint32_t, h);
}

__device__ __forceinline__ void pkfma(uint32_t& acc, uint32_t w, uint32_t h) {
  asm("v_pk_fma_f16 %0, %1, %2, %0" : "+v"(acc) : "v"(w), "v"(h));
}

__device__ __forceinline__ float cvt2f(uint32_t a) {
  f16x2 v = __builtin_bit_cast(f16x2, a);
  return (float)v.x + (float)v.y;
}

// LDS-only barrier (no vmcnt drain; producer global stores stay in flight)
__device__ __forceinline__ void step_barrier() {
  asm volatile("s_waitcnt lgkmcnt(0)" ::: "memory");
  __builtin_amdgcn_s_barrier();
}

// DPP add helper — ctrl must be a compile-time constant (builtin requirement)
template <int CTRL>
__device__ __forceinline__ float dppadd(float x) {
  int t = __builtin_amdgcn_update_dpp(0, __float_as_int(x), CTRL, 0xF, 0xF, true);
  return x + __int_as_float(t);
}
// 8-lane reduce, result valid in lanes 4-7 of each 8-group (and 12-15):
// quad_perm xor1 (0xB1), xor2 (0x4E), then row_shr:4 (0x114). Pure VALU.
__device__ __forceinline__ float red8(float x) {
  x = dppadd<0xB1>(x);
  x = dppadd<0x4E>(x);
  x = dppadd<0x114>(x);
  return x;
}

// PK skew for hbp/wlp (R8 layout): kp -> 20*(kp>>4) + (kp&15)
#define PK(kp) (20 * ((kp) >> 4) + ((kp) & 15))

#define PKQ(acc, wq, hq) { pkfma(acc, (wq).x, (hq).x); pkfma(acc, (wq).y, (hq).y); \
                           pkfma(acc, (wq).z, (hq).z); pkfma(acc, (wq).w, (hq).w); }

// ---------------------------------------------------------------------------
__device__ __forceinline__ float wval(int j, int k,
    const float* w_ll, const float* w_rl, const float* w_lr, const float* w_rr) {
  if (j < 2) return (k < 2) ? w_ll[j * 2 + k] : w_rl[j * 256 + (k - 2)];
  return (k < 2) ? w_lr[(j - 2) * 2 + k] : w_rr[(j - 2) * 256 + (k - 2)];
}

// Wp: packed f16 pairs [258][128]; Wtail: f32 [258][2] (k=256,257).
__global__ __launch_bounds__(256) void build_w_kernel(
    const float* __restrict__ w_ll, const float* __restrict__ w_rl,
    const float* __restrict__ w_lr, const float* __restrict__ w_rr,
    uint32_t* __restrict__ Wp, float* __restrict__ Wtail) {
  int i = blockIdx.x * 256 + threadIdx.x;
  if (i < 258 * 128) {
    int j = i >> 7, kp = i & 127;
    float v0 = wval(j, 2 * kp, w_ll, w_rl, w_lr, w_rr);
    float v1 = wval(j, 2 * kp + 1, w_ll, w_rl, w_lr, w_rr);
    Wp[i] = packh2(v0, v1);
  }
  if (i < 516) {
    int j = i >> 1, k = 256 + (i & 1);
    Wtail[i] = wval(j, k, w_ll, w_rl, w_lr, w_rr);
  }
}

// ---------------------------------------------------------------------------
// K_scan: 256 blocks x 768 thr (12 waves), 1 block/CU, 2 batch rows/block.
// Consumers (tid<512, 8 waves): thread (g=tid>>3, ks=tid&7) owns W rows
// {g, g+64, g+128, g+192} x k-window [32ks,32ks+32), W read from LDS
// (stride-132 rows -> conflict-free b128). DPP-only 8-lane reduce; updater
// lanes ks==4 (batch0) / ks==5 (batch1).
// Producers (tid>=512, 4 waves): per step generate C(t+1) into cbuf[(t+1)&1],
// uv(t+2) into uvstage, flush h(t-1) from sbuf to hs + zs.
// All LDS cross-talk separated by the per-step lgkm-only barrier.
// ---------------------------------------------------------------------------
__global__ __launch_bounds__(768) void rnn_scan_kernel(
    const uint32_t* __restrict__ Wp, const float* __restrict__ Wtail,
    float* __restrict__ hsC,
    const float* __restrict__ w_ro, const float* __restrict__ b_ro,
    const float* __restrict__ xs,
    const float* __restrict__ w_xl, const float* __restrict__ w_xr,
    const float* __restrict__ b_ll, const float* __restrict__ b_rr,
    uint32_t k0a, uint32_t k0b, uint32_t k1a, uint32_t k1b,
    uint32_t k2a, uint32_t k2b) {
  __shared__ __align__(16) uint32_t Wlds[256 * 132];   // 135168 B
  __shared__ __align__(16) uint32_t hbp[2][2][168];    // h packed (PK skew) + f32 tails @160,161
  __shared__ __align__(16) uint32_t wlp[2][168];       // left W rows 0,1 (PK skew) + tails
  __shared__ __align__(16) float    wtl[512];          // right-row k-tails (f32), jr-indexed
  __shared__ __align__(16) uint32_t cbuf[2][2][130];   // C(t) f16 pairs, parity-indexed
  __shared__ __align__(16) uint32_t sbuf[2][2][130];   // h(t+1) f16 pairs, parity-indexed
  __shared__ float uvstage[2][2][4];                   // {u0,u1,v0,v1} per parity/batch

  const int tid = threadIdx.x;
  const int b0 = blockIdx.x * 2;

  // ---------------- prologue staging ----------------
  for (int i = tid; i < 32768; i += 768) {
    int jr = i >> 7, kp = i & 127;
    Wlds[jr * 132 + kp] = Wp[(jr + 2) * 128 + kp];
  }
  if (tid < 256) { int row = tid >> 7, kp = tid & 127; wlp[row][PK(kp)] = Wp[row * 128 + kp]; }
  if (tid < 4)   { int row = tid >> 1; wlp[row][160 + (tid & 1)] = __float_as_uint(Wtail[row * 2 + (tid & 1)]); }
  for (int i = tid; i < 512; i += 768) wtl[i] = Wtail[i + 4];
  for (int i = tid; i < 672; i += 768) ((uint32_t*)hbp)[i] = 0u;

  // cbuf[0] <- C(t=0) (inline uv(0)); uvstage[1] <- uv(t=1)
  if (tid < 258) {
    int b = tid / 129, slot = tid - 129 * b;
    int bg = b0 + b;
    int j0 = 2 * slot;
    uint32_t o0, o1;
    float i0, i1;
    if (slot == 0) {
      tf2x32(k0a, k0b, 0u, (uint32_t)(bg * 800 + 0), o0, o1);
      float u0v = xs[bg * 800 + 0] + noise_from_bits(o0 ^ o1);
      tf2x32(k0a, k0b, 0u, (uint32_t)(bg * 800 + 1), o0, o1);
      float u1v = xs[bg * 800 + 1] + noise_from_bits(o0 ^ o1);
      i0 = w_xl[0] * u0v + w_xl[1] * u1v + b_ll[0];
      i1 = w_xl[2] * u0v + w_xl[3] * u1v + b_ll[1];
    } else {
      tf2x32(k1a, k1b, 0u, (uint32_t)(bg * 800 + 0), o0, o1);
      float v0v = xs[bg * 800 + 0] + noise_from_bits(o0 ^ o1);
      tf2x32(k1a, k1b, 0u, (uint32_t)(bg * 800 + 1), o0, o1);
      float v1v = xs[bg * 800 + 1] + noise_from_bits(o0 ^ o1);
      int jr = j0 - 2;
      i0 = fmaf(w_xr[2 * jr], v0v, fmaf(w_xr[2 * jr + 1], v1v, b_rr[jr]));
      i1 = fmaf(w_xr[2 * jr + 2], v0v, fmaf(w_xr[2 * jr + 3], v1v, b_rr[jr + 1]));
    }
    tf2x32(k2a, k2b, 0u, (uint32_t)(bg * 258 + j0), o0, o1);
    float nz0 = noise_from_bits(o0 ^ o1);
    tf2x32(k2a, k2b, 0u, (uint32_t)(bg * 258 + j0 + 1), o0, o1);
    float nz1 = noise_from_bits(o0 ^ o1);
    cbuf[0][b][slot] = packh2(i0 + nz0, i1 + nz1);
  }
  if (tid < 8) {
    int b = tid >> 2, comp = tid & 3;
    uint32_t e = (uint32_t)((b0 + b) * 800 + 2 + (comp & 1));
    uint32_t o0, o1;
    if (comp < 2) tf2x32(k0a, k0b, 0u, e, o0, o1);
    else          tf2x32(k1a, k1b, 0u, e, o0, o1);
    uvstage[1][b][comp] = xs[e] + noise_from_bits(o0 ^ o1);
  }
  __syncthreads();

  const bool isCons = (tid < 512);
  const int ks = tid & 7;
  const int g  = tid >> 3;
  const int pid = tid - 512;            // producers: [0,256)
  const float bro = b_ro[0];

  float wxl0 = 0.f, wxl1 = 0.f, wxl2 = 0.f, wxl3 = 0.f, bll0 = 0.f, bll1 = 0.f;
  if (!isCons) {
    wxl0 = w_xl[0]; wxl1 = w_xl[1]; wxl2 = w_xl[2]; wxl3 = w_xl[3];
    bll0 = b_ll[0]; bll1 = b_ll[1];
  }

  float hc0 = 0.f, hc1 = 0.f, hc2 = 0.f, hc3 = 0.f;   // right rows (updater lanes)
  float hL0 = 0.f, hL1 = 0.f;                          // left rows (lanes 4,12)

#pragma unroll 1
  for (int t = 0; t < 400; ++t) {
    const int cur = t & 1, nxt = cur ^ 1;

    if (isCons) {
      // ---- main dot: 4 rows x 2 batch x 32k = 128 pkfma, W from LDS ----
      uint32_t acc00 = 0u, acc01 = 0u, acc10 = 0u, acc11 = 0u;
      uint32_t acc20 = 0u, acc21 = 0u, acc30 = 0u, acc31 = 0u;
      const uint32_t* hb0 = &hbp[cur][0][20 * ks];
      const uint32_t* hb1 = &hbp[cur][1][20 * ks];
      const uint32_t* wb  = &Wlds[g * 132 + 16 * ks];
#pragma unroll
      for (int c = 0; c < 4; ++c) {
        u32x4 h0 = *(const u32x4*)(hb0 + 4 * c);
        u32x4 h1 = *(const u32x4*)(hb1 + 4 * c);
        u32x4 w0 = *(const u32x4*)(wb + 4 * c);
        u32x4 w1 = *(const u32x4*)(wb + 64 * 132 + 4 * c);
        u32x4 w2 = *(const u32x4*)(wb + 128 * 132 + 4 * c);
        u32x4 w3 = *(const u32x4*)(wb + 192 * 132 + 4 * c);
        PKQ(acc00, w0, h0) PKQ(acc01, w0, h1)
        PKQ(acc10, w1, h0) PKQ(acc11, w1, h1)
        PKQ(acc20, w2, h0) PKQ(acc21, w2, h1)
        PKQ(acc30, w3, h0) PKQ(acc31, w3, h1)
      }
      float a00 = red8(cvt2f(acc00)), a01 = red8(cvt2f(acc01));
      float a10 = red8(cvt2f(acc10)), a11 = red8(cvt2f(acc11));
      float a20 = red8(cvt2f(acc20)), a21 = red8(cvt2f(acc21));
      float a30 = red8(cvt2f(acc30)), a31 = red8(cvt2f(acc31));

      // ---- left rows (wave 0, lanes 0-15: lb = lane>>3) ----
      float l0 = 0.f, l1 = 0.f;
      if (tid < 16) {
        int lb = tid >> 3, kw = tid & 7;
        uint32_t lc0 = 0u, lc1 = 0u;
        const uint32_t* hb = &hbp[cur][lb][20 * kw];
#pragma unroll
        for (int c = 0; c < 4; ++c) {
          u32x4 hq = *(const u32x4*)(hb + 4 * c);
          u32x4 q0 = *(const u32x4*)&wlp[0][20 * kw + 4 * c];
          u32x4 q1 = *(const u32x4*)&wlp[1][20 * kw + 4 * c];
          PKQ(lc0, q0, hq) PKQ(lc1, q1, hq)
        }
        l0 = red8(cvt2f(lc0));
        l1 = red8(cvt2f(lc1));
      }

      // ---- right updates: lane ks==4 -> batch 0, ks==5 -> batch 1 ----
      if (ks == 4 || ks == 5) {
        const int b = ks - 4;
        float d0 = b ? a01 : a00;
        float d1 = b ? a11 : a10;
        float d2 = b ? a21 : a20;
        float d3 = b ? a31 : a30;
        float t0 = __uint_as_float(hbp[cur][b][160]);
        float t1 = __uint_as_float(hbp[cur][b][161]);
#define RUPD(RR, DD, HH) { \
        int j = g + 2 + 64 * RR; \
        float2 wt = *(const float2*)&wtl[(j - 2) * 2]; \
        f16x2 cp = __builtin_bit_cast(f16x2, cbuf[cur][b][j >> 1]); \
        float cj = (j & 1) ? (float)cp.y : (float)cp.x; \
        float pre = DD + wt.x * t0 + wt.y * t1 + cj; \
        HH = 0.8f * HH + 0.2f * my_tanh(pre); \
        if (j < 256) ((__fp16*)&hbp[nxt][b][0])[2 * PK(j >> 1) + (j & 1)] = (__fp16)HH; \
        else hbp[nxt][b][160 + (j - 256)] = __float_as_uint(HH); \
        ((__fp16*)&sbuf[cur][b][0])[2 * (j >> 1) + (j & 1)] = (__fp16)HH; }
        RUPD(0, d0, hc0)
        RUPD(1, d1, hc1)
        RUPD(2, d2, hc2)
        RUPD(3, d3, hc3)
#undef RUPD
      }

      // ---- left updates: lanes 4 (batch 0) and 12 (batch 1) ----
      if (tid < 16 && (tid & 7) == 4) {
        int lb = tid >> 3;
        float t0 = __uint_as_float(hbp[cur][lb][160]);
        float t1 = __uint_as_float(hbp[cur][lb][161]);
        f16x2 cp = __builtin_bit_cast(f16x2, cbuf[cur][lb][0]);
        float pre0 = l0 + __uint_as_float(wlp[0][160]) * t0 + __uint_as_float(wlp[0][161]) * t1 + (float)cp.x;
        float pre1 = l1 + __uint_as_float(wlp[1][160]) * t0 + __uint_as_float(wlp[1][161]) * t1 + (float)cp.y;
        hL0 = 0.8f * hL0 + 0.2f * my_tanh(pre0);
        hL1 = 0.8f * hL1 + 0.2f * my_tanh(pre1);
        hbp[nxt][lb][0] = packh2(hL0, hL1);
        sbuf[cur][lb][0] = packh2(hL0, hL1);
      }
    } else {
      // ---- producers ----
      // flush h(t-1) (sbuf[(t+1)&1]) to hs + zs(t-1)
      if (t > 0) {
        const int fp = nxt;   // (t-1)&1 == (t+1)&1
#pragma unroll
        for (int q = 0; q < 2; ++q) {
          int item = pid + 256 * q;
          if (item < 258) {
            int b = item / 129, slot = item - 129 * b;
            f16x2 hp = __builtin_bit_cast(f16x2, sbuf[fp][b][slot]);
            float* dst = hsC + (size_t)(b0 + b) * 103200 + (size_t)(t - 1) * 258 + 2 * slot;
            dst[0] = (float)hp.x;
            dst[1] = (float)hp.y;
          }
        }
        int pw = pid >> 6;
        if (pw < 2) {
          int lane = pid & 63;
          float z = 0.f;
#pragma unroll
          for (int q = 0; q < 3; ++q) {
            int slot = lane + 64 * q;
            if (slot < 129) {
              f16x2 hp = __builtin_bit_cast(f16x2, sbuf[fp][pw][slot]);
              z = fmaf((float)hp.x, w_ro[2 * slot], z);
              z = fmaf((float)hp.y, w_ro[2 * slot + 1], z);
            }
          }
#pragma unroll
          for (int m = 32; m >= 1; m >>= 1) z += __shfl_xor(z, m);
          if (lane == 0) hsC[(size_t)52838400 + (size_t)(b0 + pw) * 400 + (t - 1)] = z + bro;
        }
      }
      // generate C(t+1) into cbuf[(t+1)&1]
      if (t < 399) {
        const int tn = t + 1, pnx = nxt;
#pragma unroll
        for (int q = 0; q < 2; ++q) {
          int item = pid + 256 * q;
          if (item < 258) {
            int b = item / 129, slot = item - 129 * b;
            int bg = b0 + b;
            int j0 = 2 * slot;
            float i0, i1;
            if (slot == 0) {
              float u0v = uvstage[pnx][b][0], u1v = uvstage[pnx][b][1];
              i0 = wxl0 * u0v + wxl1 * u1v + bll0;
              i1 = wxl2 * u0v + wxl3 * u1v + bll1;
            } else {
              float v0v = uvstage[pnx][b][2], v1v = uvstage[pnx][b][3];
              int jr = j0 - 2;
              i0 = fmaf(w_xr[2 * jr], v0v, fmaf(w_xr[2 * jr + 1], v1v, b_rr[jr]));
              i1 = fmaf(w_xr[2 * jr + 2], v0v, fmaf(w_xr[2 * jr + 3], v1v, b_rr[jr + 1]));
            }
            uint32_t o0, o1;
            uint32_t base = (uint32_t)tn * 132096u + (uint32_t)bg * 258u + (uint32_t)j0;
            tf2x32(k2a, k2b, 0u, base, o0, o1);
            float nz0 = noise_from_bits(o0 ^ o1);
            tf2x32(k2a, k2b, 0u, base + 1u, o0, o1);
            float nz1 = noise_from_bits(o0 ^ o1);
            cbuf[pnx][b][slot] = packh2(i0 + nz0, i1 + nz1);
          }
        }
      }
      // uv(t+2) into uvstage[(t+2)&1]
      if (t < 398 && pid < 8) {
        int b = pid >> 2, comp = pid & 3;
        uint32_t e = (uint32_t)((b0 + b) * 800 + 2 * (t + 2) + (comp & 1));
        uint32_t o0, o1;
        if (comp < 2) tf2x32(k0a, k0b, 0u, e, o0, o1);
        else          tf2x32(k1a, k1b, 0u, e, o0, o1);
        uvstage[(t + 2) & 1][b][comp] = xs[e] + noise_from_bits(o0 ^ o1);
      }
    }

    step_barrier();
  }

  // ---------------- epilogue: flush hs[:,399] + zs(399) (sbuf[1]) ----------
  if (!isCons) {
#pragma unroll
    for (int q = 0; q < 2; ++q) {
      int item = pid + 256 * q;
      if (item < 258) {
        int b = item / 129, slot = item - 129 * b;
        f16x2 hp = __builtin_bit_cast(f16x2, sbuf[1][b][slot]);
        float* dst = hsC + (size_t)(b0 + b) * 103200 + (size_t)399 * 258 + 2 * slot;
        dst[0] = (float)hp.x;
        dst[1] = (float)hp.y;
      }
    }
    int pw = pid >> 6;
    if (pw < 2) {
      int lane = pid & 63;
      float z = 0.f;
#pragma unroll
      for (int q = 0; q < 3; ++q) {
        int slot = lane + 64 * q;
        if (slot < 129) {
          f16x2 hp = __builtin_bit_cast(f16x2, sbuf[1][pw][slot]);
          z = fmaf((float)hp.x, w_ro[2 * slot], z);
          z = fmaf((float)hp.y, w_ro[2 * slot + 1], z);
        }
      }
#pragma unroll
      for (int m = 32; m >= 1; m >>= 1) z += __shfl_xor(z, m);
      if (lane == 0) hsC[(size_t)52838400 + (size_t)(b0 + pw) * 400 + 399] = z + bro;
    }
  }
}

// ---------------------------------------------------------------------------
extern "C" void kernel_launch(void* const* d_in, const int* in_sizes, int n_in,
                              void* d_out, int out_size, void* d_ws, size_t ws_size,
                              hipStream_t stream) {
  const float* xs   = (const float*)d_in[0];
  const float* w_ll = (const float*)d_in[1];
  const float* b_ll = (const float*)d_in[2];
  const float* w_rr = (const float*)d_in[3];
  const float* b_rr = (const float*)d_in[4];
  const float* w_lr = (const float*)d_in[5];
  const float* w_rl = (const float*)d_in[6];
  const float* w_xl = (const float*)d_in[7];
  const float* w_xr = (const float*)d_in[8];
  const float* w_ro = (const float*)d_in[9];
  const float* b_ro = (const float*)d_in[10];

  float* hs = (float*)d_out;                    // 512*400*258 (+ zs after)

  uint32_t* Wp  = (uint32_t*)d_ws;              // 258*128 = 33,024 u32
  float* Wtail  = (float*)(Wp + 33024);         // 516

  uint32_t nk[3][2];
  for (uint32_t i = 0; i < 3; ++i) {
    uint32_t o0, o1;
    tf2x32(0u, 42u, 0u, i, o0, o1);
    nk[i][0] = o0; nk[i][1] = o1;
  }

  build_w_kernel<<<129, 256, 0, stream>>>(w_ll, w_rl, w_lr, w_rr, Wp, Wtail);
  rnn_scan_kernel<<<256, 768, 0, stream>>>(Wp, Wtail, hs, w_ro, b_ro, xs,
                                           w_xl, w_xr, b_ll, b_rr,
                                           nk[0][0], nk[0][1], nk[1][0], nk[1][1],
                                           nk[2][0], nk[2][1]);
}

// Round 15
// 1310.030 us; speedup vs baseline: 1.1761x; 1.1761x over previous
//
#include <hip/hip_runtime.h>
#include <stdint.h>
#include <stddef.h>

// ---------------------------------------------------------------------------
// TwoHemiRNNTanh_asymmetric_single_readout  (B=512, T=400, hidden 258)
// R15 = R8 (proven 858us scan: 512x512, 8-way ks, PK skew, asm pkfma,
// lgkm-only barriers, separate gen_uv/gen_c, zs in flush) + W parked in
// AGPRs (v_accvgpr_write once; v_accvgpr_read in-loop). R8-R12 showed the
// allocator remats/streams W from L1 every step (262KB/CU/step ~ 4100cy =
// the measured step time); AGPR values cannot be rematerialized, so W
// finally stays on-CU. R14 proved the LDS alternative loses the 2-block/CU
// overlap (1 block/CU convoy = slower despite FETCH ~ 0).
// ---------------------------------------------------------------------------

typedef uint32_t u32x4 __attribute__((ext_vector_type(4)));
typedef __fp16   f16x2 __attribute__((ext_vector_type(2)));

#define TF_ROUND(x0, x1, r) { x0 += x1; x1 = ((x1) << (r)) | ((x1) >> (32 - (r))); x1 ^= x0; }

__host__ __device__ inline void tf2x32(uint32_t k0, uint32_t k1, uint32_t x0, uint32_t x1,
                                       uint32_t& o0, uint32_t& o1) {
  uint32_t ks2 = k0 ^ k1 ^ 0x1BD11BDAu;
  x0 += k0; x1 += k1;
  TF_ROUND(x0, x1, 13) TF_ROUND(x0, x1, 15) TF_ROUND(x0, x1, 26) TF_ROUND(x0, x1, 6)
  x0 += k1; x1 += ks2 + 1u;
  TF_ROUND(x0, x1, 17) TF_ROUND(x0, x1, 29) TF_ROUND(x0, x1, 16) TF_ROUND(x0, x1, 24)
  x0 += ks2; x1 += k0 + 2u;
  TF_ROUND(x0, x1, 13) TF_ROUND(x0, x1, 15) TF_ROUND(x0, x1, 26) TF_ROUND(x0, x1, 6)
  x0 += k0; x1 += k1 + 3u;
  TF_ROUND(x0, x1, 17) TF_ROUND(x0, x1, 29) TF_ROUND(x0, x1, 16) TF_ROUND(x0, x1, 24)
  x0 += k1; x1 += ks2 + 4u;
  TF_ROUND(x0, x1, 13) TF_ROUND(x0, x1, 15) TF_ROUND(x0, x1, 26) TF_ROUND(x0, x1, 6)
  x0 += ks2; x1 += k0 + 5u;
  o0 = x0; o1 = x1;
}

__device__ __forceinline__ float jax_erfinv(float x) {
  float w = -log1pf(-x * x);
  float p;
  if (w < 5.0f) {
    w -= 2.5f;
    p = 2.81022636e-08f;
    p = fmaf(p, w, 3.43273939e-07f);
    p = fmaf(p, w, -3.5233877e-06f);
    p = fmaf(p, w, -4.39150654e-06f);
    p = fmaf(p, w, 0.00021858087f);
    p = fmaf(p, w, -0.00125372503f);
    p = fmaf(p, w, -0.00417768164f);
    p = fmaf(p, w, 0.246640727f);
    p = fmaf(p, w, 1.50140941f);
  } else {
    w = sqrtf(w) - 3.0f;
    p = -0.000200214257f;
    p = fmaf(p, w, 0.000100950558f);
    p = fmaf(p, w, 0.00134934322f);
    p = fmaf(p, w, -0.00367342844f);
    p = fmaf(p, w, 0.00573950773f);
    p = fmaf(p, w, -0.0076224613f);
    p = fmaf(p, w, 0.00943887047f);
    p = fmaf(p, w, 1.00167406f);
    p = fmaf(p, w, 2.83297682f);
  }
  return p * x;
}

__device__ __forceinline__ float uni_from_bits(uint32_t bits) {
  float f = __uint_as_float((bits >> 9) | 0x3f800000u) - 1.0f;
  float x = f * 2.0f + (-0.99999994f);
  return fmaxf(-0.99999994f, x);
}

__device__ __forceinline__ float noise_from_bits(uint32_t bits) {
  float n = 1.41421356f * jax_erfinv(uni_from_bits(bits));
  return 0.15811388f * n;   // sqrt(2/A)*SIG = sqrt(10)*0.05
}

__device__ __forceinline__ float my_tanh(float x) {
  float e = __expf(2.0f * x);
  return 1.0f - 2.0f / (e + 1.0f);
}

__device__ __forceinline__ uint32_t packh2(float a, float b) {
  f16x2 h = __builtin_amdgcn_cvt_pkrtz(a, b);
  return __builtin_bit_cast(uint32_t, h);
}

__device__ __forceinline__ void pkfma(uint32_t& acc, uint32_t w, uint32_t h) {
  asm("v_pk_fma_f16 %0, %1, %2, %0" : "+v"(acc) : "v"(w), "v"(h));
}

__device__ __forceinline__ float cvt2f(uint32_t a) {
  f16x2 v = __builtin_bit_cast(f16x2, a);
  return (float)v.x + (float)v.y;
}

// AGPR park/fetch: accvgpr_write results cannot be rematerialized from
// memory, so the 72 W dwords stay resident in the unified RF.
__device__ __forceinline__ uint32_t agpr_park(uint32_t v) {
  uint32_t a;
  asm("v_accvgpr_write_b32 %0, %1" : "=a"(a) : "v"(v));
  return a;
}
__device__ __forceinline__ uint32_t agpr_fetch(uint32_t a) {
  uint32_t v;
  asm("v_accvgpr_read_b32 %0, %1" : "=v"(v) : "a"(a));
  return v;
}

// LDS-only barrier (no vmcnt drain)
__device__ __forceinline__ void step_barrier() {
  asm volatile("s_waitcnt lgkmcnt(0)" ::: "memory");
  __builtin_amdgcn_s_barrier();
}

// 8-lane allreduce: xor1,xor2 via DPP quad_perm (VALU); xor4 via ds_swizzle.
__device__ __forceinline__ float allred8(float x) {
  int t = __builtin_amdgcn_update_dpp(0, __float_as_int(x), 0xB1, 0xF, 0xF, true);
  x += __int_as_float(t);
  t = __builtin_amdgcn_update_dpp(0, __float_as_int(x), 0x4E, 0xF, 0xF, true);
  x += __int_as_float(t);
  t = __builtin_amdgcn_ds_swizzle(__float_as_int(x), 0x101F);
  x += __int_as_float(t);
  return x;
}

// packed-slot skew: kp in [0,128) -> 20*(kp>>4) + (kp&15); spans 160 dwords.
#define PK(kp) (20 * ((kp) >> 4) + ((kp) & 15))

// ---------------------------------------------------------------------------
__device__ __forceinline__ float wval(int j, int k,
    const float* w_ll, const float* w_rl, const float* w_lr, const float* w_rr) {
  if (j < 2) return (k < 2) ? w_ll[j * 2 + k] : w_rl[j * 256 + (k - 2)];
  return (k < 2) ? w_lr[(j - 2) * 2 + k] : w_rr[(j - 2) * 256 + (k - 2)];
}

// Wp: packed f16 pairs [258][128]; Wtail: f32 [258][2] (k=256,257).
__global__ __launch_bounds__(256) void build_w_kernel(
    const float* __restrict__ w_ll, const float* __restrict__ w_rl,
    const float* __restrict__ w_lr, const float* __restrict__ w_rr,
    uint32_t* __restrict__ Wp, float* __restrict__ Wtail) {
  int i = blockIdx.x * 256 + threadIdx.x;
  if (i < 258 * 128) {
    int j = i >> 7, kp = i & 127;
    float v0 = wval(j, 2 * kp, w_ll, w_rl, w_lr, w_rr);
    float v1 = wval(j, 2 * kp + 1, w_ll, w_rl, w_lr, w_rr);
    Wp[i] = packh2(v0, v1);
  }
  if (i < 516) {
    int j = i >> 1, k = 256 + (i & 1);
    Wtail[i] = wval(j, k, w_ll, w_rl, w_lr, w_rr);
  }
}

// ---------------------------------------------------------------------------
__global__ __launch_bounds__(256) void gen_uv_kernel(
    const float* __restrict__ xs, float* __restrict__ u, float* __restrict__ v,
    uint32_t k0a, uint32_t k0b, uint32_t k1a, uint32_t k1b) {
  uint32_t i = blockIdx.x * 256u + threadIdx.x;
  bool isv = i >= 409600u;
  uint32_t e = isv ? i - 409600u : i;
  uint32_t ka = isv ? k1a : k0a;
  uint32_t kb = isv ? k1b : k0b;
  uint32_t o0, o1;
  tf2x32(ka, kb, 0u, e, o0, o1);
  float val = xs[e] + noise_from_bits(o0 ^ o1);
  if (isv) v[e] = val; else u[e] = val;
}

// ---------------------------------------------------------------------------
__global__ __launch_bounds__(256) void gen_c_kernel(
    const float* __restrict__ u, const float* __restrict__ v,
    const float* __restrict__ w_xl, const float* __restrict__ w_xr,
    const float* __restrict__ b_ll, const float* __restrict__ b_rr,
    float* __restrict__ C, uint32_t ka, uint32_t kb) {
  uint32_t i = blockIdx.x * 256u + threadIdx.x;   // < 52,838,400
  uint32_t t = i / 132096u;
  uint32_t rem = i - t * 132096u;
  uint32_t b = rem / 258u;
  uint32_t j = rem - b * 258u;
  uint32_t o0, o1;
  tf2x32(ka, kb, 0u, i, o0, o1);
  float nz = noise_from_bits(o0 ^ o1);
  uint32_t bt = (b * 400u + t) * 2u;
  float inj;
  if (j < 2u) {
    float2 uu = *(const float2*)(u + bt);
    inj = w_xl[j * 2u] * uu.x + w_xl[j * 2u + 1u] * uu.y + b_ll[j];
  } else {
    uint32_t jr = j - 2u;
    float2 vv = *(const float2*)(v + bt);
    inj = w_xr[jr * 2u] * vv.x + w_xr[jr * 2u + 1u] * vv.y + b_rr[jr];
  }
  C[(size_t)(b * 400u + t) * 258u + j] = inj + nz;
}

// ---------------------------------------------------------------------------
// K_scan: 512 blocks x 512 thr, 1 batch row/block, 2 blocks/CU.
// Thread (g=tid>>3, ks=tid&7): 4 rows (j0=2+4g) x 32 k; W parked in 72 AGPRs
// (64 main + 8 f32 tails), fetched with v_accvgpr_read in the loop.
// Dots via asm v_pk_fma_f16, f32 finalize + allred8.
// zs computed per 8-step chunk from sbuf (LDS) -> no separate zs kernel.
// ---------------------------------------------------------------------------
__global__ __launch_bounds__(512, 4) void rnn_scan_kernel(
    const uint32_t* __restrict__ Wp, const float* __restrict__ Wtail,
    float* __restrict__ hsC, const float* __restrict__ w_ro,
    const float* __restrict__ b_ro) {
  __shared__ __align__(16) uint32_t hbp[2][168];
  __shared__ __align__(16) uint32_t wlp[2][168];
  __shared__ __align__(16) float cbuf[8][260];
  __shared__ __align__(16) float sbuf[8][260];
  __shared__ __align__(16) float wrol[260];

  const int tid = threadIdx.x;
  const int ks = tid & 7;
  const int g  = tid >> 3;
  const int j0 = 2 + 4 * g;

  // persistent packed W parked in AGPRs: 4 rows x 16 k-pairs + 8 tail dwords
  uint32_t wa[64];
  uint32_t wta[8];
#pragma unroll
  for (int r = 0; r < 4; ++r) {
    const uint32_t* p = Wp + (j0 + r) * 128 + 16 * ks;
#pragma unroll
    for (int c = 0; c < 4; ++c) {
      u32x4 q = *(const u32x4*)(p + 4 * c);
      wa[r * 16 + c * 4 + 0] = agpr_park(q.x);
      wa[r * 16 + c * 4 + 1] = agpr_park(q.y);
      wa[r * 16 + c * 4 + 2] = agpr_park(q.z);
      wa[r * 16 + c * 4 + 3] = agpr_park(q.w);
    }
    float2 wtv = *(const float2*)(Wtail + (j0 + r) * 2);
    wta[2 * r]     = agpr_park(__float_as_uint(wtv.x));
    wta[2 * r + 1] = agpr_park(__float_as_uint(wtv.y));
  }
  const float bro = b_ro[0];

  // stage left-row weights (rows 0,1) packed into LDS, skewed layout
  if (tid < 256) {
    int row = tid >> 7, kp = tid & 127;
    wlp[row][PK(kp)] = Wp[row * 128 + kp];
  }
  if (tid < 4) {
    int row = tid >> 1;
    wlp[row][160 + (tid & 1)] = __float_as_uint(Wtail[row * 2 + (tid & 1)]);
  }
  if (tid < 258) {                       // w_ro remapped to jj order
    int jj = (tid < 2) ? (256 + tid) : (tid - 2);
    wrol[jj] = w_ro[tid];
  }
  for (int idx = tid; idx < 336; idx += 512) ((uint32_t*)hbp)[idx] = 0u;

  const float* gC = hsC + (size_t)blockIdx.x * 103200;
  float* gO       = hsC + (size_t)blockIdx.x * 103200;
  float* gZ       = hsC + (size_t)52838400 + (size_t)blockIdx.x * 400;

  // prologue: chunk 0 -> cbuf
  for (int idx = tid; idx < 2064; idx += 512) {
    int s = idx / 258, j = idx - 258 * s;
    int jj = (j < 2) ? (256 + j) : (j - 2);
    cbuf[s][jj] = gC[idx];
  }
  __syncthreads();

  float hcur[4] = {0.f, 0.f, 0.f, 0.f};
  float hL0 = 0.f, hL1 = 0.f;

#pragma unroll 1
  for (int cc = 0; cc < 50; ++cc) {
    float creg[5];
    const bool hn = (cc < 49);
    const int nb = (cc + 1) * 2064;
    if (hn) {
#pragma unroll
      for (int q = 0; q < 5; ++q) {
        int idx = tid + 512 * q;
        if (idx < 2064) creg[q] = gC[nb + idx];
      }
    }

#pragma unroll
    for (int s = 0; s < 8; ++s) {
      const int cur = s & 1, nxt = cur ^ 1;

      // main dot: 4 rows x 32 k as 64 v_pk_fma_f16, W fetched from AGPR
      uint32_t ac[4] = {0u, 0u, 0u, 0u};
#pragma unroll
      for (int c = 0; c < 4; ++c) {
        u32x4 hq = *(const u32x4*)&hbp[cur][20 * ks + 4 * c];
#pragma unroll
        for (int r = 0; r < 4; ++r) {
          uint32_t w0 = agpr_fetch(wa[r * 16 + c * 4 + 0]);
          uint32_t w1 = agpr_fetch(wa[r * 16 + c * 4 + 1]);
          uint32_t w2 = agpr_fetch(wa[r * 16 + c * 4 + 2]);
          uint32_t w3 = agpr_fetch(wa[r * 16 + c * 4 + 3]);
          pkfma(ac[r], w0, hq.x);
          pkfma(ac[r], w1, hq.y);
          pkfma(ac[r], w2, hq.z);
          pkfma(ac[r], w3, hq.w);
        }
      }
      float a0 = cvt2f(ac[0]);
      float a1 = cvt2f(ac[1]);
      float a2 = cvt2f(ac[2]);
      float a3 = cvt2f(ac[3]);

      // left rows (j=0,1): lanes 0..7 only
      float l0 = 0.f, l1 = 0.f;
      if (tid < 8) {
        uint32_t lc0 = 0u, lc1 = 0u;
#pragma unroll
        for (int c = 0; c < 4; ++c) {
          u32x4 hq = *(const u32x4*)&hbp[cur][20 * tid + 4 * c];
          u32x4 w0 = *(const u32x4*)&wlp[0][20 * tid + 4 * c];
          u32x4 w1 = *(const u32x4*)&wlp[1][20 * tid + 4 * c];
          pkfma(lc0, w0.x, hq.x); pkfma(lc0, w0.y, hq.y);
          pkfma(lc0, w0.z, hq.z); pkfma(lc0, w0.w, hq.w);
          pkfma(lc1, w1.x, hq.x); pkfma(lc1, w1.y, hq.y);
          pkfma(lc1, w1.z, hq.z); pkfma(lc1, w1.w, hq.w);
        }
        l0 = allred8(cvt2f(lc0));
        l1 = allred8(cvt2f(lc1));
      }

      a0 = allred8(a0); a1 = allred8(a1); a2 = allred8(a2); a3 = allred8(a3);

      const float t0 = __uint_as_float(hbp[cur][160]);
      const float t1 = __uint_as_float(hbp[cur][161]);

      // update right rows: lane ks==0 owns 4 rows (wt fetched from AGPR)
      if (ks == 0) {
        float4 cv = *(const float4*)&cbuf[s][4 * g];
        float wt00 = __uint_as_float(agpr_fetch(wta[0]));
        float wt01 = __uint_as_float(agpr_fetch(wta[1]));
        float wt10 = __uint_as_float(agpr_fetch(wta[2]));
        float wt11 = __uint_as_float(agpr_fetch(wta[3]));
        float wt20 = __uint_as_float(agpr_fetch(wta[4]));
        float wt21 = __uint_as_float(agpr_fetch(wta[5]));
        float wt30 = __uint_as_float(agpr_fetch(wta[6]));
        float wt31 = __uint_as_float(agpr_fetch(wta[7]));
        float pre0 = a0 + wt00 * t0 + wt01 * t1 + cv.x;
        float pre1 = a1 + wt10 * t0 + wt11 * t1 + cv.y;
        float pre2 = a2 + wt20 * t0 + wt21 * t1 + cv.z;
        float pre3 = a3 + wt30 * t0 + wt31 * t1 + cv.w;
        hcur[0] = 0.8f * hcur[0] + 0.2f * my_tanh(pre0);
        hcur[1] = 0.8f * hcur[1] + 0.2f * my_tanh(pre1);
        hcur[2] = 0.8f * hcur[2] + 0.2f * my_tanh(pre2);
        hcur[3] = 0.8f * hcur[3] + 0.2f * my_tanh(pre3);
        uint32_t p01 = packh2(hcur[0], hcur[1]);
        uint32_t p23 = packh2(hcur[2], hcur[3]);
        if (g == 63) {               // rows 254,255 packed; 256,257 f32 tail
          hbp[nxt][PK(127)] = p01;
          hbp[nxt][160] = __float_as_uint(hcur[2]);
          hbp[nxt][161] = __float_as_uint(hcur[3]);
        } else {
          hbp[nxt][PK(1 + 2 * g)] = p01;
          hbp[nxt][PK(2 + 2 * g)] = p23;
        }
        *(float4*)&sbuf[s][4 * g] = make_float4(hcur[0], hcur[1], hcur[2], hcur[3]);
      }

      // left updater: lane 0 owns rows 0,1 (h[0],h[1] -> pair kp=0)
      if (tid == 0) {
        float wl0t0 = __uint_as_float(wlp[0][160]);
        float wl0t1 = __uint_as_float(wlp[0][161]);
        float wl1t0 = __uint_as_float(wlp[1][160]);
        float wl1t1 = __uint_as_float(wlp[1][161]);
        float pre0 = l0 + wl0t0 * t0 + wl0t1 * t1 + cbuf[s][256];
        float pre1 = l1 + wl1t0 * t0 + wl1t1 * t1 + cbuf[s][257];
        hL0 = 0.8f * hL0 + 0.2f * my_tanh(pre0);
        hL1 = 0.8f * hL1 + 0.2f * my_tanh(pre1);
        hbp[nxt][0] = packh2(hL0, hL1);   // PK(0) == 0
        sbuf[s][256] = hL0;
        sbuf[s][257] = hL1;
      }

      step_barrier();
    }

    // flush sbuf -> hs (coalesced)
    const int fb = cc * 2064;
    for (int idx = tid; idx < 2064; idx += 512) {
      int s = idx / 258, j = idx - 258 * s;
      int jj = (j < 2) ? (256 + j) : (j - 2);
      gO[fb + idx] = sbuf[s][jj];
    }

    // zs for the chunk's 8 timesteps: wave w handles s=w
    {
      int w = tid >> 6, lane = tid & 63;
      float zacc = 0.f;
#pragma unroll
      for (int q = 0; q < 5; ++q) {
        int jj = lane + 64 * q;
        if (jj < 258) zacc = fmaf(sbuf[w][jj], wrol[jj], zacc);
      }
#pragma unroll
      for (int m = 32; m >= 1; m >>= 1) zacc += __shfl_xor(zacc, m);
      if (lane == 0) gZ[cc * 8 + w] = zacc + bro;
    }

    // commit prefetched C chunk -> cbuf (vmcnt wait lands here, once/chunk)
    if (hn) {
#pragma unroll
      for (int q = 0; q < 5; ++q) {
        int idx = tid + 512 * q;
        if (idx < 2064) {
          int s = idx / 258, j = idx - 258 * s;
          int jj = (j < 2) ? (256 + j) : (j - 2);
          cbuf[s][jj] = creg[q];
        }
      }
    }
    step_barrier();
  }
}

// ---------------------------------------------------------------------------
extern "C" void kernel_launch(void* const* d_in, const int* in_sizes, int n_in,
                              void* d_out, int out_size, void* d_ws, size_t ws_size,
                              hipStream_t stream) {
  const float* xs   = (const float*)d_in[0];
  const float* w_ll = (const float*)d_in[1];
  const float* b_ll = (const float*)d_in[2];
  const float* w_rr = (const float*)d_in[3];
  const float* b_rr = (const float*)d_in[4];
  const float* w_lr = (const float*)d_in[5];
  const float* w_rl = (const float*)d_in[6];
  const float* w_xl = (const float*)d_in[7];
  const float* w_xr = (const float*)d_in[8];
  const float* w_ro = (const float*)d_in[9];
  const float* b_ro = (const float*)d_in[10];

  float* hs = (float*)d_out;                    // 512*400*258 (+ zs after)

  uint32_t* Wp  = (uint32_t*)d_ws;              // 258*128 = 33,024 u32
  float* Wtail  = (float*)(Wp + 33024);         // 516
  float* u      = Wtail + 516;                  // 409,600
  float* v      = u + 409600;                   // 409,600

  uint32_t nk[3][2];
  for (uint32_t i = 0; i < 3; ++i) {
    uint32_t o0, o1;
    tf2x32(0u, 42u, 0u, i, o0, o1);
    nk[i][0] = o0; nk[i][1] = o1;
  }

  build_w_kernel<<<129, 256, 0, stream>>>(w_ll, w_rl, w_lr, w_rr, Wp, Wtail);
  gen_uv_kernel<<<3200, 256, 0, stream>>>(xs, u, v, nk[0][0], nk[0][1], nk[1][0], nk[1][1]);
  gen_c_kernel<<<206400, 256, 0, stream>>>(u, v, w_xl, w_xr, b_ll, b_rr, hs, nk[2][0], nk[2][1]);
  rnn_scan_kernel<<<512, 512, 0, stream>>>(Wp, Wtail, hs, w_ro, b_ro);
}

// Round 16
// 910.655 us; speedup vs baseline: 1.6920x; 1.4386x over previous
//
#include <hip/hip_runtime.h>
#include <stdint.h>
#include <stddef.h>

// ---------------------------------------------------------------------------
// TwoHemiRNNTanh_asymmetric_single_readout  (B=512, T=400, hidden 258)
// R16: matvec moved to the MFMA pipe. Per step, per block (1 batch row):
// D[16x256] = A(h,16x32-tiles) x B(W^T) via 16 v_mfma_f32_16x16x32_f16
// per wave (2 N-tiles x 8 K-tiles). W fragments = 64 VGPRs loaded ONCE via
// asm volatile global_load (non-remat, non-dup -> stays resident; no per-use
// accvgpr_read like R15). k-reduce is inside MFMA (no DPP/swizzle). A-reads
// are 4-address LDS broadcasts. Left rows j=0,1: R8 scalar path on wave 0.
// k=256/257 tails scalar in update. 512 blocks x 512 thr, 2 blocks/CU.
// ---------------------------------------------------------------------------

typedef uint32_t u32x4 __attribute__((ext_vector_type(4)));
typedef __fp16   f16x2 __attribute__((ext_vector_type(2)));
typedef __fp16   f16x8 __attribute__((ext_vector_type(8)));
typedef float    f32x4 __attribute__((ext_vector_type(4)));

#define TF_ROUND(x0, x1, r) { x0 += x1; x1 = ((x1) << (r)) | ((x1) >> (32 - (r))); x1 ^= x0; }

__host__ __device__ inline void tf2x32(uint32_t k0, uint32_t k1, uint32_t x0, uint32_t x1,
                                       uint32_t& o0, uint32_t& o1) {
  uint32_t ks2 = k0 ^ k1 ^ 0x1BD11BDAu;
  x0 += k0; x1 += k1;
  TF_ROUND(x0, x1, 13) TF_ROUND(x0, x1, 15) TF_ROUND(x0, x1, 26) TF_ROUND(x0, x1, 6)
  x0 += k1; x1 += ks2 + 1u;
  TF_ROUND(x0, x1, 17) TF_ROUND(x0, x1, 29) TF_ROUND(x0, x1, 16) TF_ROUND(x0, x1, 24)
  x0 += ks2; x1 += k0 + 2u;
  TF_ROUND(x0, x1, 13) TF_ROUND(x0, x1, 15) TF_ROUND(x0, x1, 26) TF_ROUND(x0, x1, 6)
  x0 += k0; x1 += k1 + 3u;
  TF_ROUND(x0, x1, 17) TF_ROUND(x0, x1, 29) TF_ROUND(x0, x1, 16) TF_ROUND(x0, x1, 24)
  x0 += k1; x1 += ks2 + 4u;
  TF_ROUND(x0, x1, 13) TF_ROUND(x0, x1, 15) TF_ROUND(x0, x1, 26) TF_ROUND(x0, x1, 6)
  x0 += ks2; x1 += k0 + 5u;
  o0 = x0; o1 = x1;
}

__device__ __forceinline__ float jax_erfinv(float x) {
  float w = -log1pf(-x * x);
  float p;
  if (w < 5.0f) {
    w -= 2.5f;
    p = 2.81022636e-08f;
    p = fmaf(p, w, 3.43273939e-07f);
    p = fmaf(p, w, -3.5233877e-06f);
    p = fmaf(p, w, -4.39150654e-06f);
    p = fmaf(p, w, 0.00021858087f);
    p = fmaf(p, w, -0.00125372503f);
    p = fmaf(p, w, -0.00417768164f);
    p = fmaf(p, w, 0.246640727f);
    p = fmaf(p, w, 1.50140941f);
  } else {
    w = sqrtf(w) - 3.0f;
    p = -0.000200214257f;
    p = fmaf(p, w, 0.000100950558f);
    p = fmaf(p, w, 0.00134934322f);
    p = fmaf(p, w, -0.00367342844f);
    p = fmaf(p, w, 0.00573950773f);
    p = fmaf(p, w, -0.0076224613f);
    p = fmaf(p, w, 0.00943887047f);
    p = fmaf(p, w, 1.00167406f);
    p = fmaf(p, w, 2.83297682f);
  }
  return p * x;
}

__device__ __forceinline__ float uni_from_bits(uint32_t bits) {
  float f = __uint_as_float((bits >> 9) | 0x3f800000u) - 1.0f;
  float x = f * 2.0f + (-0.99999994f);
  return fmaxf(-0.99999994f, x);
}

__device__ __forceinline__ float noise_from_bits(uint32_t bits) {
  float n = 1.41421356f * jax_erfinv(uni_from_bits(bits));
  return 0.15811388f * n;   // sqrt(2/A)*SIG = sqrt(10)*0.05
}

__device__ __forceinline__ float my_tanh(float x) {
  float e = __expf(2.0f * x);
  return 1.0f - 2.0f / (e + 1.0f);
}

__device__ __forceinline__ uint32_t packh2(float a, float b) {
  f16x2 h = __builtin_amdgcn_cvt_pkrtz(a, b);
  return __builtin_bit_cast(uint32_t, h);
}

__device__ __forceinline__ void pkfma(uint32_t& acc, uint32_t w, uint32_t h) {
  asm("v_pk_fma_f16 %0, %1, %2, %0" : "+v"(acc) : "v"(w), "v"(h));
}

__device__ __forceinline__ float cvt2f(uint32_t a) {
  f16x2 v = __builtin_bit_cast(f16x2, a);
  return (float)v.x + (float)v.y;
}

// pinned global load: asm volatile result cannot be rematerialized or
// duplicated -> the W fragments stay register-resident for the whole kernel.
__device__ __forceinline__ u32x4 vload_pin(const uint32_t* p) {
  u32x4 r;
  asm volatile("global_load_dwordx4 %0, %1, off\n\ts_waitcnt vmcnt(0)"
               : "=v"(r) : "v"(p) : "memory");
  return r;
}

// LDS-only barrier (no vmcnt drain)
__device__ __forceinline__ void step_barrier() {
  asm volatile("s_waitcnt lgkmcnt(0)" ::: "memory");
  __builtin_amdgcn_s_barrier();
}

// 8-lane allreduce (left rows): xor1,xor2 DPP; xor4 ds_swizzle.
__device__ __forceinline__ float allred8(float x) {
  int t = __builtin_amdgcn_update_dpp(0, __float_as_int(x), 0xB1, 0xF, 0xF, true);
  x += __int_as_float(t);
  t = __builtin_amdgcn_update_dpp(0, __float_as_int(x), 0x4E, 0xF, 0xF, true);
  x += __int_as_float(t);
  t = __builtin_amdgcn_ds_swizzle(__float_as_int(x), 0x101F);
  x += __int_as_float(t);
  return x;
}

// ---------------------------------------------------------------------------
__device__ __forceinline__ float wval(int j, int k,
    const float* w_ll, const float* w_rl, const float* w_lr, const float* w_rr) {
  if (j < 2) return (k < 2) ? w_ll[j * 2 + k] : w_rl[j * 256 + (k - 2)];
  return (k < 2) ? w_lr[(j - 2) * 2 + k] : w_rr[(j - 2) * 256 + (k - 2)];
}

// Wp: packed f16 pairs [258][128]; Wtail: f32 [258][2] (k=256,257).
__global__ __launch_bounds__(256) void build_w_kernel(
    const float* __restrict__ w_ll, const float* __restrict__ w_rl,
    const float* __restrict__ w_lr, const float* __restrict__ w_rr,
    uint32_t* __restrict__ Wp, float* __restrict__ Wtail) {
  int i = blockIdx.x * 256 + threadIdx.x;
  if (i < 258 * 128) {
    int j = i >> 7, kp = i & 127;
    float v0 = wval(j, 2 * kp, w_ll, w_rl, w_lr, w_rr);
    float v1 = wval(j, 2 * kp + 1, w_ll, w_rl, w_lr, w_rr);
    Wp[i] = packh2(v0, v1);
  }
  if (i < 516) {
    int j = i >> 1, k = 256 + (i & 1);
    Wtail[i] = wval(j, k, w_ll, w_rl, w_lr, w_rr);
  }
}

// ---------------------------------------------------------------------------
__global__ __launch_bounds__(256) void gen_uv_kernel(
    const float* __restrict__ xs, float* __restrict__ u, float* __restrict__ v,
    uint32_t k0a, uint32_t k0b, uint32_t k1a, uint32_t k1b) {
  uint32_t i = blockIdx.x * 256u + threadIdx.x;
  bool isv = i >= 409600u;
  uint32_t e = isv ? i - 409600u : i;
  uint32_t ka = isv ? k1a : k0a;
  uint32_t kb = isv ? k1b : k0b;
  uint32_t o0, o1;
  tf2x32(ka, kb, 0u, e, o0, o1);
  float val = xs[e] + noise_from_bits(o0 ^ o1);
  if (isv) v[e] = val; else u[e] = val;
}

// ---------------------------------------------------------------------------
__global__ __launch_bounds__(256) void gen_c_kernel(
    const float* __restrict__ u, const float* __restrict__ v,
    const float* __restrict__ w_xl, const float* __restrict__ w_xr,
    const float* __restrict__ b_ll, const float* __restrict__ b_rr,
    float* __restrict__ C, uint32_t ka, uint32_t kb) {
  uint32_t i = blockIdx.x * 256u + threadIdx.x;   // < 52,838,400
  uint32_t t = i / 132096u;
  uint32_t rem = i - t * 132096u;
  uint32_t b = rem / 258u;
  uint32_t j = rem - b * 258u;
  uint32_t o0, o1;
  tf2x32(ka, kb, 0u, i, o0, o1);
  float nz = noise_from_bits(o0 ^ o1);
  uint32_t bt = (b * 400u + t) * 2u;
  float inj;
  if (j < 2u) {
    float2 uu = *(const float2*)(u + bt);
    inj = w_xl[j * 2u] * uu.x + w_xl[j * 2u + 1u] * uu.y + b_ll[j];
  } else {
    uint32_t jr = j - 2u;
    float2 vv = *(const float2*)(v + bt);
    inj = w_xr[jr * 2u] * vv.x + w_xr[jr * 2u + 1u] * vv.y + b_rr[jr];
  }
  C[(size_t)(b * 400u + t) * 258u + j] = inj + nz;
}

// ---------------------------------------------------------------------------
// K_scan: 512 blocks x 512 thr (8 waves), 1 batch row/block, 2 blocks/CU.
// Wave w: output cols j in [32w+2, 32w+34) via 2 MFMA N-tiles; B fragments
// (W^T tiles) pinned in 64 VGPRs. A = h (row 0 of M=16), read per K-tile as
// one broadcast ds_read_b128. Lanes 0-15 of each wave update 2 cols each.
// Left rows j=0,1: wave-0 scalar pkfma path (wlp flat in LDS).
// ---------------------------------------------------------------------------
__global__ __launch_bounds__(512, 4) void rnn_scan_kernel(
    const uint32_t* __restrict__ Wp, const float* __restrict__ Wtail,
    float* __restrict__ hsC, const float* __restrict__ w_ro,
    const float* __restrict__ b_ro) {
  __shared__ __align__(16) uint32_t hA[2][132];   // h packed f16 (dw = j>>1)
  __shared__ float htail[2][2];                   // h[256], h[257] f32
  __shared__ __align__(16) uint32_t wlp[2][128];  // W rows 0,1 packed, flat
  __shared__ __align__(16) float wtl[520];        // Wtail f32, all 258 rows
  __shared__ __align__(16) float cbuf[8][260];    // C chunk, natural j order
  __shared__ __align__(16) float sbuf[8][260];    // h out chunk, natural j
  __shared__ float wrol[260];

  const int tid  = threadIdx.x;
  const int lane = tid & 63;
  const int wv   = tid >> 6;        // wave id [0,8)
  const int lq   = lane >> 4;       // k-subgroup [0,4)

  // ---- pinned B fragments: 2 N-tiles x 8 K-tiles x 4 dwords = 64 VGPR ----
  u32x4 B0[8], B1[8];
  {
    const int j0 = 32 * wv + 2 + (lane & 15);     // tile0 col -> W row j0
    const uint32_t* base0 = Wp + (size_t)j0 * 128 + 4 * lq;
    const uint32_t* base1 = base0 + 16 * 128;     // tile1: j0 + 16
#pragma unroll
    for (int kt = 0; kt < 8; ++kt) {
      B0[kt] = vload_pin(base0 + 16 * kt);
      B1[kt] = vload_pin(base1 + 16 * kt);
    }
  }
  const float bro = b_ro[0];

  // ---- staging ----
  if (tid < 256) wlp[tid >> 7][tid & 127] = Wp[(size_t)(tid >> 7) * 128 + (tid & 127)];
  if (tid < 258) wrol[tid] = w_ro[tid];
  for (int i = tid; i < 516; i += 512) wtl[i] = Wtail[i];
  for (int i = tid; i < 264; i += 512) ((uint32_t*)hA)[i] = 0u;
  if (tid < 4) ((float*)htail)[tid] = 0.f;

  const float* gC = hsC + (size_t)blockIdx.x * 103200;
  float* gO       = hsC + (size_t)blockIdx.x * 103200;
  float* gZ       = hsC + (size_t)52838400 + (size_t)blockIdx.x * 400;

  // prologue: chunk 0 -> cbuf (natural order)
  for (int idx = tid; idx < 2064; idx += 512) {
    int s = idx / 258, j = idx - 258 * s;
    cbuf[s][j] = gC[idx];
  }
  __syncthreads();

  float hp0 = 0.f, hp1 = 0.f;       // persistent h for this lane's 2 cols
  float hL0 = 0.f, hL1 = 0.f;       // left rows (lane 0 of wave 0)

#pragma unroll 1
  for (int cc = 0; cc < 50; ++cc) {
    float creg[5];
    const bool hn = (cc < 49);
    const int nb = (cc + 1) * 2064;
    if (hn) {
#pragma unroll
      for (int q = 0; q < 5; ++q) {
        int idx = tid + 512 * q;
        if (idx < 2064) creg[q] = gC[nb + idx];
      }
    }

#pragma unroll
    for (int s = 0; s < 8; ++s) {
      const int cur = s & 1, nxt = cur ^ 1;

      // ---- MFMA matvec: D = A(h) x B(W^T), 16 MFMA per wave ----
      f32x4 d0 = {0.f, 0.f, 0.f, 0.f};
      f32x4 d1 = {0.f, 0.f, 0.f, 0.f};
      const uint32_t* ha = hA[cur];
#pragma unroll
      for (int kt = 0; kt < 8; ++kt) {
        u32x4 av = *(const u32x4*)(ha + 16 * kt + 4 * lq);   // broadcast read
        f16x8 af = __builtin_bit_cast(f16x8, av);
        d0 = __builtin_amdgcn_mfma_f32_16x16x32_f16(af, __builtin_bit_cast(f16x8, B0[kt]), d0, 0, 0, 0);
        d1 = __builtin_amdgcn_mfma_f32_16x16x32_f16(af, __builtin_bit_cast(f16x8, B1[kt]), d1, 0, 0, 0);
      }

      // ---- left rows j=0,1 (wave 0, lanes 0..7; execz-skipped elsewhere) --
      float l0 = 0.f, l1 = 0.f;
      if (tid < 8) {
        uint32_t lc0 = 0u, lc1 = 0u;
#pragma unroll
        for (int c = 0; c < 4; ++c) {
          u32x4 hq = *(const u32x4*)&hA[cur][16 * tid + 4 * c];
          u32x4 w0 = *(const u32x4*)&wlp[0][16 * tid + 4 * c];
          u32x4 w1 = *(const u32x4*)&wlp[1][16 * tid + 4 * c];
          pkfma(lc0, w0.x, hq.x); pkfma(lc0, w0.y, hq.y);
          pkfma(lc0, w0.z, hq.z); pkfma(lc0, w0.w, hq.w);
          pkfma(lc1, w1.x, hq.x); pkfma(lc1, w1.y, hq.y);
          pkfma(lc1, w1.z, hq.z); pkfma(lc1, w1.w, hq.w);
        }
        l0 = allred8(cvt2f(lc0));
        l1 = allred8(cvt2f(lc1));
      }

      const float t0v = htail[cur][0];
      const float t1v = htail[cur][1];

      // ---- updates: lanes 0-15 of each wave own 2 cols (D row 0 = reg .x)
      if (lane < 16) {
        {
          int j = 32 * wv + 2 + lane;                       // tile 0 col
          float2 wt2 = *(const float2*)&wtl[2 * j];
          float pre = d0.x + wt2.x * t0v + wt2.y * t1v + cbuf[s][j];
          hp0 = 0.8f * hp0 + 0.2f * my_tanh(pre);
          sbuf[s][j] = hp0;
          ((__fp16*)hA[nxt])[j] = (__fp16)hp0;              // j<256 always
        }
        {
          int j = 32 * wv + 18 + lane;                      // tile 1 col
          float2 wt2 = *(const float2*)&wtl[2 * j];
          float pre = d1.x + wt2.x * t0v + wt2.y * t1v + cbuf[s][j];
          hp1 = 0.8f * hp1 + 0.2f * my_tanh(pre);
          sbuf[s][j] = hp1;
          if (j < 256) ((__fp16*)hA[nxt])[j] = (__fp16)hp1;
          else         htail[nxt][j - 256] = hp1;           // h[256],h[257]
        }
      }

      // ---- left update: lane 0 (wave 0) ----
      if (tid == 0) {
        float pre0 = l0 + wtl[0] * t0v + wtl[1] * t1v + cbuf[s][0];
        float pre1 = l1 + wtl[2] * t0v + wtl[3] * t1v + cbuf[s][1];
        hL0 = 0.8f * hL0 + 0.2f * my_tanh(pre0);
        hL1 = 0.8f * hL1 + 0.2f * my_tanh(pre1);
        hA[nxt][0] = packh2(hL0, hL1);                      // halfwords 0,1
        sbuf[s][0] = hL0;
        sbuf[s][1] = hL1;
      }

      step_barrier();
    }

    // ---- flush sbuf -> hs (coalesced, natural order) ----
    const int fb = cc * 2064;
#pragma unroll
    for (int q = 0; q < 5; ++q) {
      int idx = tid + 512 * q;
      if (idx < 2064) {
        int s = idx / 258, j = idx - 258 * s;
        gO[fb + idx] = sbuf[s][j];
      }
    }

    // ---- zs: wave wv handles step-slot s = wv ----
    {
      float zacc = 0.f;
#pragma unroll
      for (int q = 0; q < 5; ++q) {
        int jj = lane + 64 * q;
        if (jj < 258) zacc = fmaf(sbuf[wv][jj], wrol[jj], zacc);
      }
#pragma unroll
      for (int m = 32; m >= 1; m >>= 1) zacc += __shfl_xor(zacc, m);
      if (lane == 0) gZ[cc * 8 + wv] = zacc + bro;
    }

    // ---- commit prefetched C chunk (vmcnt wait lands here, once/chunk) ----
    if (hn) {
#pragma unroll
      for (int q = 0; q < 5; ++q) {
        int idx = tid + 512 * q;
        if (idx < 2064) {
          int s = idx / 258, j = idx - 258 * s;
          cbuf[s][j] = creg[q];
        }
      }
    }
    step_barrier();
  }
}

// ---------------------------------------------------------------------------
extern "C" void kernel_launch(void* const* d_in, const int* in_sizes, int n_in,
                              void* d_out, int out_size, void* d_ws, size_t ws_size,
                              hipStream_t stream) {
  const float* xs   = (const float*)d_in[0];
  const float* w_ll = (const float*)d_in[1];
  const float* b_ll = (const float*)d_in[2];
  const float* w_rr = (const float*)d_in[3];
  const float* b_rr = (const float*)d_in[4];
  const float* w_lr = (const float*)d_in[5];
  const float* w_rl = (const float*)d_in[6];
  const float* w_xl = (const float*)d_in[7];
  const float* w_xr = (const float*)d_in[8];
  const float* w_ro = (const float*)d_in[9];
  const float* b_ro = (const float*)d_in[10];

  float* hs = (float*)d_out;                    // 512*400*258 (+ zs after)

  uint32_t* Wp  = (uint32_t*)d_ws;              // 258*128 = 33,024 u32
  float* Wtail  = (float*)(Wp + 33024);         // 516
  float* u      = Wtail + 516;                  // 409,600
  float* v      = u + 409600;                   // 409,600

  uint32_t nk[3][2];
  for (uint32_t i = 0; i < 3; ++i) {
    uint32_t o0, o1;
    tf2x32(0u, 42u, 0u, i, o0, o1);
    nk[i][0] = o0; nk[i][1] = o1;
  }

  build_w_kernel<<<129, 256, 0, stream>>>(w_ll, w_rl, w_lr, w_rr, Wp, Wtail);
  gen_uv_kernel<<<3200, 256, 0, stream>>>(xs, u, v, nk[0][0], nk[0][1], nk[1][0], nk[1][1]);
  gen_c_kernel<<<206400, 256, 0, stream>>>(u, v, w_xl, w_xr, b_ll, b_rr, hs, nk[2][0], nk[2][1]);
  rnn_scan_kernel<<<512, 512, 0, stream>>>(Wp, Wtail, hs, w_ro, b_ro);
}